// Round 12
// baseline (545.855 us; speedup 1.0000x reference)
//
#include <hip/hip_runtime.h>

typedef float  f4     __attribute__((ext_vector_type(4)));
typedef float  f32x4  __attribute__((ext_vector_type(4)));
typedef short  short8 __attribute__((ext_vector_type(8)));
typedef __bf16 bf16x8 __attribute__((ext_vector_type(8)));
typedef int    int4v  __attribute__((ext_vector_type(4)));
typedef unsigned short us4 __attribute__((ext_vector_type(4)));

__device__ __forceinline__ unsigned short f2bf(float f) {
    unsigned int u = __builtin_bit_cast(unsigned int, f);
    u += 0x7FFFu + ((u >> 16) & 1u);
    return (unsigned short)(u >> 16);
}
__device__ __forceinline__ float bf2f(unsigned short h) {
    unsigned int u = ((unsigned int)h) << 16;
    return __builtin_bit_cast(float, u);
}
__device__ __forceinline__ f32x4 mfma_bf16(short8 a, short8 b, f32x4 c) {
    return __builtin_amdgcn_mfma_f32_16x16x32_bf16(
        __builtin_bit_cast(bf16x8, a), __builtin_bit_cast(bf16x8, b), c, 0, 0, 0);
}
// v_cvt_pk_bf16_f32: src0 -> D[15:0], src1 -> D[31:16]
__device__ __forceinline__ int cvt_pk_bf16(float lo, float hi) {
    int d;
    asm("v_cvt_pk_bf16_f32 %0, %1, %2" : "=v"(d) : "v"(lo), "v"(hi));
    return d;
}
__device__ __forceinline__ int bperm(int addr, int src) {
    return __builtin_amdgcn_ds_bpermute(addr, src);
}

// ============================================================================
// Weight pre-conversion: fold LN gamma into Wq/Wk, cvt to bf16, store
// FRAGMENT-MAJOR: frag short-index = mat*65536 + ((ct*8 + k)*64 + lane)*8 + e
//   content[e] = W'[cout = ct*16 + (lane&15)][cin = k*32 + (lane>>4)*8 + e]
// ws: [0]Wq' [128K]Wk' [256K]Wv [384K]Wo
//     [512K] f32 consts: qc float2[256] {rsq,cbq} | kc float2[256] {rsk,cbk}
// ============================================================================
__global__ void pcaf_precvt(const float* __restrict__ Wq, const float* __restrict__ bq,
                            const float* __restrict__ Wk, const float* __restrict__ bk,
                            const float* __restrict__ Wv, const float* __restrict__ Wo,
                            const float* __restrict__ g_lf, const float* __restrict__ b_lf,
                            const float* __restrict__ g_hf, const float* __restrict__ b_hf,
                            void* __restrict__ ws) {
    const int mat  = blockIdx.x >> 8;      // 0=q 1=k 2=v 3=o
    const int row  = blockIdx.x & 255;     // cout
    const int lane = threadIdx.x;          // 0..63, 4 cin each
    const float* W = (mat == 0) ? Wq : (mat == 1) ? Wk : (mat == 2) ? Wv : Wo;
    f4 w = *(const f4*)(W + row * 256 + lane * 4);
    f4 wp = w;
    if (mat < 2) {
        const float* g = mat ? g_hf : g_lf;
        f4 gg = *(const f4*)(g + lane * 4);
        wp = w * gg;
    }
    us4 u;
    u[0] = f2bf(wp[0]); u[1] = f2bf(wp[1]); u[2] = f2bf(wp[2]); u[3] = f2bf(wp[3]);
    {
        const int ct   = row >> 4;
        const int l15r = row & 15;
        const int k_   = lane >> 3;          // cin block of 32
        const int g_   = (lane >> 1) & 3;    // 8-cin group
        const int e4   = (lane & 1) * 4;     // half of the 8-cin group
        unsigned short* dst = (unsigned short*)ws + mat * 65536 +
                              (((ct * 8 + k_) * 64) + g_ * 16 + l15r) * 8 + e4;
        *(us4*)dst = u;
    }
    if (mat < 2) {
        const float* b = mat ? b_hf : b_lf;
        f4 bb = *(const f4*)(b + lane * 4);
        float rsum = wp[0] + wp[1] + wp[2] + wp[3];
        float cb   = bb[0] * w[0] + bb[1] * w[1] + bb[2] * w[2] + bb[3] * w[3];
        #pragma unroll
        for (int d = 1; d < 64; d <<= 1) {
            rsum += __shfl_xor(rsum, d);
            cb   += __shfl_xor(cb, d);
        }
        if (lane == 0) {
            float* cons = (float*)((char*)ws + 524288);
            cons[mat * 512 + 2 * row]     = rsum;
            cons[mat * 512 + 2 * row + 1] = cb + (mat ? bk[row] : bq[row]);
        }
    }
}

// ============================================================================
// Main fused kernel: 1024 threads (16 waves), ONE WINDOW PAIR per block.
// Q/K via TRANSPOSED GEMMs -> in-register LN + repack (no LDS round-trip).
// 4 barriers; {V,K,Q GEMM + attention} runs barrier-free.
// ============================================================================
constexpr int RS  = 528;         // bf16 tile row stride (16B aligned)
constexpr int HWC = 65536;       // H*W
constexpr int Wd  = 256;
constexpr int OA  = 0;           // lf raw (128 tok) -> O        (67584)
constexpr int OB  = 67584;       // hf raw (128 tok), stays raw  (67584)
constexpr int OS  = 135168;      // LN stats

struct AccW { f32x4 a[4][2]; };  // rows = token tiles, cols = 2 cout tiles
struct AccT { f32x4 a[2][4]; };  // rows = 2 cout tiles, cols = 4 token tiles

// Original orientation: A = token rows from LDS, B = weight frags.
__device__ __forceinline__ AccW gemmW(const char* base,
                                      const unsigned short* __restrict__ Wbw,
                                      int lane, int g, int l15) {
    AccW r;
    f32x4 z = {0.f, 0.f, 0.f, 0.f};
    #pragma unroll
    for (int m = 0; m < 4; ++m) { r.a[m][0] = z; r.a[m][1] = z; }
    #pragma unroll
    for (int half = 0; half < 2; ++half) {
        short8 w0[4], w1[4];
        #pragma unroll
        for (int k = 0; k < 4; ++k) {
            w0[k] = *(const short8*)(Wbw + (half * 4 + k) * 512 + lane * 8);
            w1[k] = *(const short8*)(Wbw + 4096 + (half * 4 + k) * 512 + lane * 8);
        }
        #pragma unroll
        for (int k = 0; k < 4; ++k) {
            #pragma unroll
            for (int m = 0; m < 4; ++m) {
                short8 am = *(const short8*)(base + (16 * m + l15) * RS +
                                             ((half * 4 + k) * 32 + g * 8) * 2);
                r.a[m][0] = mfma_bf16(am, w0[k], r.a[m][0]);
                r.a[m][1] = mfma_bf16(am, w1[k], r.a[m][1]);
            }
        }
    }
    return r;
}

// Transposed orientation: A = weight frags, B = token rows -> C[cout][token].
__device__ __forceinline__ AccT gemmWT(const char* base,
                                       const unsigned short* __restrict__ Wbw,
                                       int lane, int g, int l15) {
    AccT r;
    f32x4 z = {0.f, 0.f, 0.f, 0.f};
    #pragma unroll
    for (int n = 0; n < 4; ++n) { r.a[0][n] = z; r.a[1][n] = z; }
    #pragma unroll
    for (int half = 0; half < 2; ++half) {
        short8 w0[4], w1[4];
        #pragma unroll
        for (int k = 0; k < 4; ++k) {
            w0[k] = *(const short8*)(Wbw + (half * 4 + k) * 512 + lane * 8);
            w1[k] = *(const short8*)(Wbw + 4096 + (half * 4 + k) * 512 + lane * 8);
        }
        #pragma unroll
        for (int k = 0; k < 4; ++k) {
            #pragma unroll
            for (int n = 0; n < 4; ++n) {
                short8 tk = *(const short8*)(base + (16 * n + l15) * RS +
                                             ((half * 4 + k) * 32 + g * 8) * 2);
                r.a[0][n] = mfma_bf16(w0[k], tk, r.a[0][n]);
                r.a[1][n] = mfma_bf16(w1[k], tk, r.a[1][n]);
            }
        }
    }
    return r;
}

// C-layout -> A/B-frag repack (the proven V pattern): two m-variants + ghi.
__device__ __forceinline__ short8 repack4(const int* p0, const int* p1,
                                          int a0, int a1, bool ghi) {
    int4v t;
    #pragma unroll
    for (int j = 0; j < 4; ++j) {
        int ad = (j >> 1) ? a1 : a0;
        int v0 = bperm(ad, p0[j & 1]);
        int v1 = bperm(ad, p1[j & 1]);
        t[j] = ghi ? v1 : v0;
    }
    return __builtin_bit_cast(short8, t);
}

__global__ __attribute__((amdgpu_flat_work_group_size(1024, 1024)))
void pcaf12_kernel(
    const float* __restrict__ y_lf, const float* __restrict__ y_hf,
    const float* __restrict__ bv, const float* __restrict__ bo,
    const void* __restrict__ ws, float* __restrict__ out)
{
    __shared__ __align__(16) char sm[137216];

    const unsigned short* wsq = (const unsigned short*)ws;
    const unsigned short* wsk = wsq + 65536;
    const unsigned short* wsv = wsq + 131072;
    const unsigned short* wso = wsq + 196608;
    const float* qc = (const float*)((const char*)ws + 524288);
    const float* kc = qc + 512;

    const int tid = threadIdx.x;
    const int bid = blockIdx.x;                      // 0..2047
    const int wi  = ((bid & 7) << 8) | (bid >> 3);   // XCD-contiguous chunks
    const int bb  = wi >> 9;                         // batch 0..3
    const int nh  = (wi >> 4) & 31;
    const int nwp = wi & 15;                         // window-pair column
    const long pair_base = (long)bb * 256 * HWC + (long)(nh * 8) * Wd + nwp * 16;

    const int wave = tid >> 6;        // 0..15
    const int win  = wave >> 3;       // 0,1 within the pair
    const int head = wave & 7;
    const int lane = tid & 63;
    const int g    = lane >> 4;
    const int l15  = lane & 15;
    const int c0   = 32 * head + l15;
    const int ro   = win * 64;        // token-row offset of this wave's window

    // ---- P0: stage pair as bf16; full-64B-line reads -----------------------
    {
        f4 lv[8], hv[8];
        #pragma unroll
        for (int it = 0; it < 4; ++it) {
            int q2  = it * 1024 + tid;       // 0..4095
            int c2  = q2 >> 5;               // channel pair 0..127
            int ph  = (q2 >> 2) & 7;
            int pw4 = (q2 & 3) * 4;          // 0,4,8,12 across the pair
            long go = pair_base + (long)(2 * c2) * HWC + ph * Wd + pw4;
            lv[2 * it]     = *(const f4*)(y_lf + go);
            lv[2 * it + 1] = *(const f4*)(y_lf + go + HWC);
            hv[2 * it]     = *(const f4*)(y_hf + go);
            hv[2 * it + 1] = *(const f4*)(y_hf + go + HWC);
        }
        #pragma unroll
        for (int it = 0; it < 4; ++it) {
            int q2  = it * 1024 + tid;
            int c2  = q2 >> 5;
            int ph  = (q2 >> 2) & 7;
            int pw4 = (q2 & 3) * 4;
            int tok0 = (pw4 >> 3) * 64 + ph * 8 + (pw4 & 7);
            #pragma unroll
            for (int j = 0; j < 4; ++j) {
                unsigned int lvv = (unsigned int)f2bf(lv[2 * it][j]) | ((unsigned int)f2bf(lv[2 * it + 1][j]) << 16);
                unsigned int hvv = (unsigned int)f2bf(hv[2 * it][j]) | ((unsigned int)f2bf(hv[2 * it + 1][j]) << 16);
                *(unsigned int*)(sm + OA + (tok0 + j) * RS + c2 * 4) = lvv;
                *(unsigned int*)(sm + OB + (tok0 + j) * RS + c2 * 4) = hvv;
            }
        }
    }
    __syncthreads();   // BAR1

    // ---- P1: LN stats for all 128 token-rows, both tensors -----------------
    {
        const int t = tid >> 3, j = tid & 7;     // t: 0..127
        #pragma unroll
        for (int pass = 0; pass < 2; ++pass) {
            const int base = pass ? OB : OA;
            float sum = 0.f, ss = 0.f;
            #pragma unroll
            for (int r = 0; r < 4; ++r) {
                short8 raw = *(const short8*)(sm + base + t * RS + (j * 32 + r * 8) * 2);
                #pragma unroll
                for (int e = 0; e < 8; ++e) { float f = bf2f((unsigned short)raw[e]); sum += f; ss += f * f; }
            }
            sum += __shfl_xor(sum, 1); ss += __shfl_xor(ss, 1);
            sum += __shfl_xor(sum, 2); ss += __shfl_xor(ss, 2);
            sum += __shfl_xor(sum, 4); ss += __shfl_xor(ss, 4);
            float mean = sum * (1.f / 256.f);
            float rstd = rsqrtf(ss * (1.f / 256.f) - mean * mean + 1e-5f);
            if (j == 0) {
                float* S = (float*)(sm + OS);
                S[pass * 256 + t]       = mean;
                S[pass * 256 + 128 + t] = rstd;
            }
        }
    }
    __syncthreads();   // BAR2 (stats ready; tiles stable, all reads below)

    const float* S = (const float*)(sm + OS);
    const int  a0  = ((2 * (g & 1)) * 16 + l15) * 4;
    const int  a1  = a0 + 64;
    const bool ghi = (g >> 1) & 1;
    f32x4 z = {0.f, 0.f, 0.f, 0.f};

    // ---- V GEMM (original orientation) -> vf frags in regs -----------------
    short8 vf[2][2];
    {
        AccW vacc = gemmW(sm + OB + ro * RS, wsv + head * 8192, lane, g, l15);
        float bv0 = bv[c0], bv1 = bv[c0 + 16];
        int vp[4][2][2];
        #pragma unroll
        for (int m = 0; m < 4; ++m) {
            vp[m][0][0] = cvt_pk_bf16(vacc.a[m][0][0] + bv0, vacc.a[m][0][1] + bv0);
            vp[m][0][1] = cvt_pk_bf16(vacc.a[m][0][2] + bv0, vacc.a[m][0][3] + bv0);
            vp[m][1][0] = cvt_pk_bf16(vacc.a[m][1][0] + bv1, vacc.a[m][1][1] + bv1);
            vp[m][1][1] = cvt_pk_bf16(vacc.a[m][1][2] + bv1, vacc.a[m][1][3] + bv1);
        }
        #pragma unroll
        for (int kk = 0; kk < 2; ++kk)
            #pragma unroll
            for (int n2 = 0; n2 < 2; ++n2)
                vf[kk][n2] = repack4(vp[2 * kk][n2], vp[2 * kk + 1][n2], a0, a1, ghi);
    }

    // ---- K GEMM (transposed) -> in-reg LN -> kf frags ----------------------
    short8 kf[4];
    {
        AccT kacc = gemmWT(sm + OB + ro * RS, wsk + head * 8192, lane, g, l15);
        float mh[4], rh[4];
        #pragma unroll
        for (int n = 0; n < 4; ++n) {
            mh[n] = S[256 + ro + 16 * n + l15];
            rh[n] = S[384 + ro + 16 * n + l15];
        }
        int kp[2][4][2];
        #pragma unroll
        for (int m = 0; m < 2; ++m) {
            int cb = 32 * head + 16 * m + 4 * g;
            f4 c0v = *(const f4*)(kc + cb * 2);
            f4 c1v = *(const f4*)(kc + cb * 2 + 4);
            #pragma unroll
            for (int n = 0; n < 4; ++n) {
                float v0 = rh[n] * (kacc.a[m][n][0] - mh[n] * c0v[0]) + c0v[1];
                float v1 = rh[n] * (kacc.a[m][n][1] - mh[n] * c0v[2]) + c0v[3];
                float v2 = rh[n] * (kacc.a[m][n][2] - mh[n] * c1v[0]) + c1v[1];
                float v3 = rh[n] * (kacc.a[m][n][3] - mh[n] * c1v[2]) + c1v[3];
                kp[m][n][0] = cvt_pk_bf16(v0, v1);
                kp[m][n][1] = cvt_pk_bf16(v2, v3);
            }
        }
        #pragma unroll
        for (int x = 0; x < 4; ++x)
            kf[x] = repack4(kp[0][x], kp[1][x], a0, a1, ghi);
    }

    // ---- Q GEMM (transposed) -> in-reg LN+scale -> qf frags ----------------
    short8 qf[4];
    {
        AccT qacc = gemmWT(sm + OA + ro * RS, wsq + head * 8192, lane, g, l15);
        const float SCALE = 0.17677669529663687f;   // 1/sqrt(32)
        float ml[4], rl[4];
        #pragma unroll
        for (int n = 0; n < 4; ++n) {
            ml[n] = S[ro + 16 * n + l15];
            rl[n] = S[128 + ro + 16 * n + l15];
        }
        int qp[2][4][2];
        #pragma unroll
        for (int m = 0; m < 2; ++m) {
            int cb = 32 * head + 16 * m + 4 * g;
            f4 c0v = *(const f4*)(qc + cb * 2);
            f4 c1v = *(const f4*)(qc + cb * 2 + 4);
            #pragma unroll
            for (int n = 0; n < 4; ++n) {
                float v0 = (rl[n] * (qacc.a[m][n][0] - ml[n] * c0v[0]) + c0v[1]) * SCALE;
                float v1 = (rl[n] * (qacc.a[m][n][1] - ml[n] * c0v[2]) + c0v[3]) * SCALE;
                float v2 = (rl[n] * (qacc.a[m][n][2] - ml[n] * c1v[0]) + c1v[1]) * SCALE;
                float v3 = (rl[n] * (qacc.a[m][n][3] - ml[n] * c1v[2]) + c1v[3]) * SCALE;
                qp[m][n][0] = cvt_pk_bf16(v0, v1);
                qp[m][n][1] = cvt_pk_bf16(v2, v3);
            }
        }
        #pragma unroll
        for (int x = 0; x < 4; ++x)
            qf[x] = repack4(qp[0][x], qp[1][x], a0, a1, ghi);
    }

    // ---- attention: fully in registers -------------------------------------
    f32x4 o[4][2];
    {
        #pragma unroll
        for (int c = 0; c < 4; ++c) { o[c][0] = z; o[c][1] = z; }

        #pragma unroll
        for (int c = 0; c < 4; ++c) {
            f32x4 stc[4];
            #pragma unroll
            for (int nk = 0; nk < 4; ++nk)
                stc[nk] = mfma_bf16(kf[nk], qf[c], z);

            float mx = stc[0][0];
            #pragma unroll
            for (int nk = 0; nk < 4; ++nk)
                #pragma unroll
                for (int i = 0; i < 4; ++i) mx = fmaxf(mx, stc[nk][i]);
            mx = fmaxf(mx, __shfl_xor(mx, 16));
            mx = fmaxf(mx, __shfl_xor(mx, 32));
            float sum = 0.f;
            #pragma unroll
            for (int nk = 0; nk < 4; ++nk)
                #pragma unroll
                for (int i = 0; i < 4; ++i) {
                    float e = __expf(stc[nk][i] - mx);
                    stc[nk][i] = e;
                    sum += e;
                }
            sum += __shfl_xor(sum, 16);
            sum += __shfl_xor(sum, 32);
            float is = 1.f / sum;

            int pq[4][2];
            #pragma unroll
            for (int nk = 0; nk < 4; ++nk) {
                pq[nk][0] = cvt_pk_bf16(stc[nk][0] * is, stc[nk][1] * is);
                pq[nk][1] = cvt_pk_bf16(stc[nk][2] * is, stc[nk][3] * is);
            }

            #pragma unroll
            for (int kk = 0; kk < 2; ++kk) {
                short8 pf = repack4(pq[2 * kk], pq[2 * kk + 1], a0, a1, ghi);
                o[c][0] = mfma_bf16(pf, vf[kk][0], o[c][0]);
                o[c][1] = mfma_bf16(pf, vf[kk][1], o[c][1]);
            }
        }
    }
    __syncthreads();   // BAR3 (all raw-A reads done block-wide)

    // ---- O -> A region (rows=tokens, cols=couts) ---------------------------
    #pragma unroll
    for (int c = 0; c < 4; ++c)
        #pragma unroll
        for (int i = 0; i < 4; ++i) {
            int t = ro + 16 * c + 4 * g + i;
            *(unsigned short*)(sm + OA + t * RS + c0 * 2)        = f2bf(o[c][0][i]);
            *(unsigned short*)(sm + OA + t * RS + (c0 + 16) * 2) = f2bf(o[c][1][i]);
        }
    __syncthreads();   // BAR4

    // ---- P5: out-proj + bias + residual (from raw B), direct f4 stores -----
    {
        AccW oacc = gemmW(sm + OA + ro * RS, wso + head * 8192, lane, g, l15);
        const long win_base = pair_base + win * 8;
        float bo0 = bo[c0], bo1 = bo[c0 + 16];
        #pragma unroll
        for (int n = 0; n < 2; ++n) {
            float bon = n ? bo1 : bo0;
            int cout = c0 + 16 * n;
            #pragma unroll
            for (int m = 0; m < 4; ++m) {
                int tok0 = 16 * m + 4 * g;
                int ph = tok0 >> 3, pw = tok0 & 7;
                f4 ov;
                #pragma unroll
                for (int i = 0; i < 4; ++i) {
                    float rv = bf2f(*(const unsigned short*)(
                        sm + OB + (ro + tok0 + i) * RS + cout * 2));
                    ov[i] = oacc.a[m][n][i] + bon + rv;
                }
                *(f4*)(out + win_base + (long)cout * HWC + ph * Wd + pw) = ov;
            }
        }
    }
}

extern "C" void kernel_launch(void* const* d_in, const int* in_sizes, int n_in,
                              void* d_out, int out_size, void* d_ws, size_t ws_size,
                              hipStream_t stream) {
    (void)in_sizes; (void)n_in; (void)out_size; (void)ws_size;
    const float* y_lf = (const float*)d_in[0];
    const float* y_hf = (const float*)d_in[1];
    const float* g_lf = (const float*)d_in[2];
    const float* b_lf = (const float*)d_in[3];
    const float* g_hf = (const float*)d_in[4];
    const float* b_hf = (const float*)d_in[5];
    const float* Wq   = (const float*)d_in[6];
    const float* bq   = (const float*)d_in[7];
    const float* Wk   = (const float*)d_in[8];
    const float* bk   = (const float*)d_in[9];
    const float* Wv   = (const float*)d_in[10];
    const float* bv   = (const float*)d_in[11];
    const float* Wo   = (const float*)d_in[12];
    const float* bo   = (const float*)d_in[13];
    float* out = (float*)d_out;

    pcaf_precvt<<<dim3(1024), dim3(64), 0, stream>>>(
        Wq, bq, Wk, bk, Wv, Wo, g_lf, b_lf, g_hf, b_hf, d_ws);
    pcaf12_kernel<<<dim3(2048), dim3(1024), 0, stream>>>(
        y_lf, y_hf, bv, bo, d_ws, out);
}

// Round 13
// 491.866 us; speedup vs baseline: 1.1098x; 1.1098x over previous
//
#include <hip/hip_runtime.h>

typedef float  f4     __attribute__((ext_vector_type(4)));
typedef float  f32x4  __attribute__((ext_vector_type(4)));
typedef short  short8 __attribute__((ext_vector_type(8)));
typedef __bf16 bf16x8 __attribute__((ext_vector_type(8)));
typedef int    int4v  __attribute__((ext_vector_type(4)));
typedef unsigned short us4 __attribute__((ext_vector_type(4)));

__device__ __forceinline__ unsigned short f2bf(float f) {
    unsigned int u = __builtin_bit_cast(unsigned int, f);
    u += 0x7FFFu + ((u >> 16) & 1u);
    return (unsigned short)(u >> 16);
}
__device__ __forceinline__ float bf2f(unsigned short h) {
    unsigned int u = ((unsigned int)h) << 16;
    return __builtin_bit_cast(float, u);
}
__device__ __forceinline__ f32x4 mfma_bf16(short8 a, short8 b, f32x4 c) {
    return __builtin_amdgcn_mfma_f32_16x16x32_bf16(
        __builtin_bit_cast(bf16x8, a), __builtin_bit_cast(bf16x8, b), c, 0, 0, 0);
}
__device__ __forceinline__ int cvt_pk_bf16(float lo, float hi) {
    int d;
    asm volatile("v_cvt_pk_bf16_f32 %0, %1, %2" : "=v"(d) : "v"(lo), "v"(hi));
    return d;
}
__device__ __forceinline__ int bperm(int addr, int src) {
    return __builtin_amdgcn_ds_bpermute(addr, src);
}

// ============================================================================
// Weight pre-conversion: fold LN gamma into Wq/Wk, cvt to bf16, store
// FRAGMENT-MAJOR: frag short-index = mat*65536 + ((ct*8 + k)*64 + lane)*8 + e
//   content[e] = W'[cout = ct*16 + (lane&15)][cin = k*32 + (lane>>4)*8 + e]
// ws: [0]Wq' [128K]Wk' [256K]Wv [384K]Wo
//     [512K] f32 consts: rsq[256]|cbq[256]|rsk[256]|cbk[256]
// ============================================================================
__global__ void pcaf_precvt(const float* __restrict__ Wq, const float* __restrict__ bq,
                            const float* __restrict__ Wk, const float* __restrict__ bk,
                            const float* __restrict__ Wv, const float* __restrict__ Wo,
                            const float* __restrict__ g_lf, const float* __restrict__ b_lf,
                            const float* __restrict__ g_hf, const float* __restrict__ b_hf,
                            void* __restrict__ ws) {
    const int mat  = blockIdx.x >> 8;      // 0=q 1=k 2=v 3=o
    const int row  = blockIdx.x & 255;     // cout
    const int lane = threadIdx.x;          // 0..63, 4 cin each
    const float* W = (mat == 0) ? Wq : (mat == 1) ? Wk : (mat == 2) ? Wv : Wo;
    f4 w = *(const f4*)(W + row * 256 + lane * 4);
    f4 wp = w;
    if (mat < 2) {
        const float* g = mat ? g_hf : g_lf;
        f4 gg = *(const f4*)(g + lane * 4);
        wp = w * gg;
    }
    us4 u;
    u[0] = f2bf(wp[0]); u[1] = f2bf(wp[1]); u[2] = f2bf(wp[2]); u[3] = f2bf(wp[3]);
    {
        const int ct   = row >> 4;
        const int l15r = row & 15;
        const int k_   = lane >> 3;          // cin block of 32
        const int g_   = (lane >> 1) & 3;    // 8-cin group
        const int e4   = (lane & 1) * 4;     // half of the 8-cin group
        unsigned short* dst = (unsigned short*)ws + mat * 65536 +
                              (((ct * 8 + k_) * 64) + g_ * 16 + l15r) * 8 + e4;
        *(us4*)dst = u;
    }
    if (mat < 2) {
        const float* b = mat ? b_hf : b_lf;
        f4 bb = *(const f4*)(b + lane * 4);
        float rsum = wp[0] + wp[1] + wp[2] + wp[3];
        float cb   = bb[0] * w[0] + bb[1] * w[1] + bb[2] * w[2] + bb[3] * w[3];
        #pragma unroll
        for (int d = 1; d < 64; d <<= 1) {
            rsum += __shfl_xor(rsum, d);
            cb   += __shfl_xor(cb, d);
        }
        if (lane == 0) {
            float* cons = (float*)((char*)ws + 524288);
            cons[mat * 512 + row]       = rsum;
            cons[mat * 512 + 256 + row] = cb + (mat ? bk[row] : bq[row]);
        }
    }
}

// ============================================================================
// Main fused kernel: 1024 threads (16 waves), ONE WINDOW PAIR per block.
// Round-6 structure; P0 remapped so staging writes are bank-conflict-free
// (thread = (tensor, channel-pair, pw-strip), loop over ph).
// ============================================================================
constexpr int RS  = 528;         // bf16 tile row stride (16B aligned)
constexpr int HWC = 65536;       // H*W
constexpr int Wd  = 256;
constexpr int OA  = 0;           // lf raw (128 tok) -> Q -> O   (67584)
constexpr int OB  = 67584;       // hf raw (128 tok) -> K        (67584)
constexpr int OS  = 135168;      // LN stats

struct AccW { f32x4 a[4][2]; };

__device__ __forceinline__ AccW gemmW(const char* base,
                                      const unsigned short* __restrict__ Wbw,
                                      int lane, int g, int l15) {
    AccW r;
    f32x4 z = {0.f, 0.f, 0.f, 0.f};
    #pragma unroll
    for (int m = 0; m < 4; ++m) { r.a[m][0] = z; r.a[m][1] = z; }
    #pragma unroll
    for (int half = 0; half < 2; ++half) {
        short8 w0[4], w1[4];
        #pragma unroll
        for (int k = 0; k < 4; ++k) {
            w0[k] = *(const short8*)(Wbw + (half * 4 + k) * 512 + lane * 8);
            w1[k] = *(const short8*)(Wbw + 4096 + (half * 4 + k) * 512 + lane * 8);
        }
        #pragma unroll
        for (int k = 0; k < 4; ++k) {
            #pragma unroll
            for (int m = 0; m < 4; ++m) {
                short8 am = *(const short8*)(base + (16 * m + l15) * RS +
                                             ((half * 4 + k) * 32 + g * 8) * 2);
                r.a[m][0] = mfma_bf16(am, w0[k], r.a[m][0]);
                r.a[m][1] = mfma_bf16(am, w1[k], r.a[m][1]);
            }
        }
    }
    return r;
}

__global__ __attribute__((amdgpu_flat_work_group_size(1024, 1024)))
void pcaf13_kernel(
    const float* __restrict__ y_lf, const float* __restrict__ y_hf,
    const float* __restrict__ bv, const float* __restrict__ bo,
    const void* __restrict__ ws, float* __restrict__ out)
{
    __shared__ __align__(16) char sm[137216];

    const unsigned short* wsq = (const unsigned short*)ws;
    const unsigned short* wsk = wsq + 65536;
    const unsigned short* wsv = wsq + 131072;
    const unsigned short* wso = wsq + 196608;
    const float* cons = (const float*)((const char*)ws + 524288);

    const int tid = threadIdx.x;
    const int bid = blockIdx.x;                      // 0..2047
    const int wi  = ((bid & 7) << 8) | (bid >> 3);   // XCD-contiguous chunks
    const int bb  = wi >> 9;                         // batch 0..3
    const int nh  = (wi >> 4) & 31;
    const int nwp = wi & 15;                         // window-pair column
    const long pair_base = (long)bb * 256 * HWC + (long)(nh * 8) * Wd + nwp * 16;

    const int wave = tid >> 6;        // 0..15
    const int win  = wave >> 3;       // 0,1 within the pair
    const int head = wave & 7;
    const int lane = tid & 63;
    const int g    = lane >> 4;
    const int l15  = lane & 15;
    const int c0   = 32 * head + l15;
    const int ro   = win * 64;        // token-row offset of this wave's window

    // ---- P0: stage pair as bf16; conflict-free LDS writes ------------------
    // thread = (tensor=tid>>9, channel-pair c2=(tid&511)>>2, pw-strip (tid&3)*4)
    // loops over ph. Writes per wave span banks {0..31} at 2 lanes/bank (free).
    {
        const int half = tid >> 9;           // 0: lf, 1: hf (wave-uniform)
        const int t9   = tid & 511;
        const int pw4  = (t9 & 3) * 4;
        const int c2   = t9 >> 2;            // 0..127
        const float* src = half ? y_hf : y_lf;
        const int dst  = half ? OB : OA;
        const float* gp = src + pair_base + (long)(2 * c2) * HWC + pw4;
        #pragma unroll
        for (int hh = 0; hh < 2; ++hh) {
            f4 v0[4], v1[4];
            #pragma unroll
            for (int p = 0; p < 4; ++p) {
                int ph = hh * 4 + p;
                v0[p] = *(const f4*)(gp + ph * Wd);
                v1[p] = *(const f4*)(gp + ph * Wd + HWC);
            }
            #pragma unroll
            for (int p = 0; p < 4; ++p) {
                int ph = hh * 4 + p;
                int tok0 = (pw4 >> 3) * 64 + ph * 8 + (pw4 & 7);
                #pragma unroll
                for (int j = 0; j < 4; ++j) {
                    unsigned int pk = (unsigned int)f2bf(v0[p][j]) |
                                      ((unsigned int)f2bf(v1[p][j]) << 16);
                    *(unsigned int*)(sm + dst + (tok0 + j) * RS + c2 * 4) = pk;
                }
            }
        }
    }
    __syncthreads();   // BAR1

    // ---- P1: LN stats for all 128 token-rows, both tensors -----------------
    {
        const int t = tid >> 3, j = tid & 7;     // t: 0..127
        #pragma unroll
        for (int pass = 0; pass < 2; ++pass) {
            const int base = pass ? OB : OA;
            float sum = 0.f, ss = 0.f;
            #pragma unroll
            for (int r = 0; r < 4; ++r) {
                short8 raw = *(const short8*)(sm + base + t * RS + (j * 32 + r * 8) * 2);
                #pragma unroll
                for (int e = 0; e < 8; ++e) { float f = bf2f((unsigned short)raw[e]); sum += f; ss += f * f; }
            }
            sum += __shfl_xor(sum, 1); ss += __shfl_xor(ss, 1);
            sum += __shfl_xor(sum, 2); ss += __shfl_xor(ss, 2);
            sum += __shfl_xor(sum, 4); ss += __shfl_xor(ss, 4);
            float mean = sum * (1.f / 256.f);
            float rstd = rsqrtf(ss * (1.f / 256.f) - mean * mean + 1e-5f);
            if (j == 0) {
                float* S = (float*)(sm + OS);
                S[pass * 256 + t]       = mean;
                S[pass * 256 + 128 + t] = rstd;
            }
        }
    }

    // ---- Q GEMM (reads raw A rows of this window); qacc stays live ---------
    AccW qacc = gemmW(sm + OA + ro * RS, wsq + head * 8192, lane, g, l15);

    // ---- residual (raw hf) -> packed bf16 regs -----------------------------
    unsigned int resp[4][2][2];
    #pragma unroll
    for (int m = 0; m < 4; ++m)
        #pragma unroll
        for (int n = 0; n < 2; ++n)
            #pragma unroll
            for (int jh = 0; jh < 2; ++jh) {
                unsigned int lo = *(const unsigned short*)(sm + OB + (ro + 16 * m + 4 * g + 2 * jh) * RS + (c0 + 16 * n) * 2);
                unsigned int hi = *(const unsigned short*)(sm + OB + (ro + 16 * m + 4 * g + 2 * jh + 1) * RS + (c0 + 16 * n) * 2);
                resp[m][n][jh] = lo | (hi << 16);
            }

    // ---- V GEMM (reads raw B); pack V (+bv) to bf16 pairs in regs ----------
    int vp[4][2][2];
    {
        AccW vacc = gemmW(sm + OB + ro * RS, wsv + head * 8192, lane, g, l15);
        float bv0 = bv[c0], bv1 = bv[c0 + 16];
        #pragma unroll
        for (int m = 0; m < 4; ++m) {
            vp[m][0][0] = cvt_pk_bf16(vacc.a[m][0][0] + bv0, vacc.a[m][0][1] + bv0);
            vp[m][0][1] = cvt_pk_bf16(vacc.a[m][0][2] + bv0, vacc.a[m][0][3] + bv0);
            vp[m][1][0] = cvt_pk_bf16(vacc.a[m][1][0] + bv1, vacc.a[m][1][1] + bv1);
            vp[m][1][1] = cvt_pk_bf16(vacc.a[m][1][2] + bv1, vacc.a[m][1][3] + bv1);
        }
    }
    __syncthreads();   // BAR2 (all raw-A reads done)

    // ---- Q epilogue (LN folded, scaled) -> A; qacc dies --------------------
    {
        const float* S = (const float*)(sm + OS);
        const float SCALE = 0.17677669529663687f;   // 1/sqrt(32)
        float rs0 = cons[c0], rs1 = cons[c0 + 16];
        float cb0 = cons[256 + c0], cb1 = cons[256 + c0 + 16];
        #pragma unroll
        for (int m = 0; m < 4; ++m)
            #pragma unroll
            for (int i = 0; i < 4; ++i) {
                int t = ro + 16 * m + 4 * g + i;
                float mean = S[t], rstd = S[128 + t];
                float v0 = (rstd * (qacc.a[m][0][i] - mean * rs0) + cb0) * SCALE;
                float v1 = (rstd * (qacc.a[m][1][i] - mean * rs1) + cb1) * SCALE;
                *(unsigned short*)(sm + OA + t * RS + c0 * 2)        = f2bf(v0);
                *(unsigned short*)(sm + OA + t * RS + (c0 + 16) * 2) = f2bf(v1);
            }
    }

    // ---- K GEMM (reads raw B) ----------------------------------------------
    AccW kacc = gemmW(sm + OB + ro * RS, wsk + head * 8192, lane, g, l15);
    __syncthreads();   // BAR2b (all raw-B reads done)

    // ---- K epilogue (LN folded) -> B; kacc dies ----------------------------
    {
        const float* S = (const float*)(sm + OS);
        float rk0 = cons[512 + c0], rk1 = cons[512 + c0 + 16];
        float ck0 = cons[768 + c0], ck1 = cons[768 + c0 + 16];
        #pragma unroll
        for (int m = 0; m < 4; ++m)
            #pragma unroll
            for (int i = 0; i < 4; ++i) {
                int t = ro + 16 * m + 4 * g + i;
                float mean = S[256 + t], rstd = S[384 + t];
                float v0 = rstd * (kacc.a[m][0][i] - mean * rk0) + ck0;
                float v1 = rstd * (kacc.a[m][1][i] - mean * rk1) + ck1;
                *(unsigned short*)(sm + OB + t * RS + c0 * 2)        = f2bf(v0);
                *(unsigned short*)(sm + OB + t * RS + (c0 + 16) * 2) = f2bf(v1);
            }
    }
    __syncthreads();   // BAR3 (Q,K ready in LDS)

    // ---- P4: attention, one wave per (window, head) ------------------------
    {
        short8 kf[4], qf[4];
        #pragma unroll
        for (int x = 0; x < 4; ++x) {
            kf[x] = *(const short8*)(sm + OB + (ro + 16 * x + l15) * RS + (32 * head + 8 * g) * 2);
            qf[x] = *(const short8*)(sm + OA + (ro + 16 * x + l15) * RS + (32 * head + 8 * g) * 2);
        }
        __syncthreads();   // BAR3b (frag reads done; A overwritten below)

        f32x4 z = {0.f, 0.f, 0.f, 0.f};
        const int a0 = ((2 * (g & 1)) * 16 + l15) * 4;
        const int a1 = a0 + 64;
        const bool ghi = (g >> 1) & 1;

        short8 vf[2][2];
        #pragma unroll
        for (int kk = 0; kk < 2; ++kk)
            #pragma unroll
            for (int n2 = 0; n2 < 2; ++n2) {
                int4v t;
                #pragma unroll
                for (int j = 0; j < 4; ++j) {
                    int ad = (j >> 1) ? a1 : a0;
                    int v0 = bperm(ad, vp[2 * kk][n2][j & 1]);
                    int v1 = bperm(ad, vp[2 * kk + 1][n2][j & 1]);
                    t[j] = ghi ? v1 : v0;
                }
                vf[kk][n2] = __builtin_bit_cast(short8, t);
            }

        f32x4 o[4][2];
        #pragma unroll
        for (int c = 0; c < 4; ++c) { o[c][0] = z; o[c][1] = z; }

        #pragma unroll
        for (int c = 0; c < 4; ++c) {
            f32x4 stc[4];
            #pragma unroll
            for (int nk = 0; nk < 4; ++nk)
                stc[nk] = mfma_bf16(kf[nk], qf[c], z);

            float mx = stc[0][0];
            #pragma unroll
            for (int nk = 0; nk < 4; ++nk)
                #pragma unroll
                for (int i = 0; i < 4; ++i) mx = fmaxf(mx, stc[nk][i]);
            mx = fmaxf(mx, __shfl_xor(mx, 16));
            mx = fmaxf(mx, __shfl_xor(mx, 32));
            float sum = 0.f;
            #pragma unroll
            for (int nk = 0; nk < 4; ++nk)
                #pragma unroll
                for (int i = 0; i < 4; ++i) {
                    float e = __expf(stc[nk][i] - mx);
                    stc[nk][i] = e;
                    sum += e;
                }
            sum += __shfl_xor(sum, 16);
            sum += __shfl_xor(sum, 32);
            float is = 1.f / sum;

            int pq[4][2];
            #pragma unroll
            for (int nk = 0; nk < 4; ++nk) {
                pq[nk][0] = cvt_pk_bf16(stc[nk][0] * is, stc[nk][1] * is);
                pq[nk][1] = cvt_pk_bf16(stc[nk][2] * is, stc[nk][3] * is);
            }

            #pragma unroll
            for (int kk = 0; kk < 2; ++kk) {
                int4v t;
                #pragma unroll
                for (int j = 0; j < 4; ++j) {
                    int ad = (j >> 1) ? a1 : a0;
                    int v0 = bperm(ad, pq[2 * kk][j & 1]);
                    int v1 = bperm(ad, pq[2 * kk + 1][j & 1]);
                    t[j] = ghi ? v1 : v0;
                }
                short8 pf = __builtin_bit_cast(short8, t);
                o[c][0] = mfma_bf16(pf, vf[kk][0], o[c][0]);
                o[c][1] = mfma_bf16(pf, vf[kk][1], o[c][1]);
            }
        }

        // O -> A region (rows=tokens, cols=couts)
        #pragma unroll
        for (int c = 0; c < 4; ++c)
            #pragma unroll
            for (int i = 0; i < 4; ++i) {
                int t = ro + 16 * c + 4 * g + i;
                *(unsigned short*)(sm + OA + t * RS + c0 * 2)        = f2bf(o[c][0][i]);
                *(unsigned short*)(sm + OA + t * RS + (c0 + 16) * 2) = f2bf(o[c][1][i]);
            }
    }
    __syncthreads();   // BAR4

    // ---- P5: out-proj + bias + residual, full-line float4 stores -----------
    {
        AccW oacc = gemmW(sm + OA + ro * RS, wso + head * 8192, lane, g, l15);
        const long win_base = pair_base + win * 8;
        float bo0 = bo[c0], bo1 = bo[c0 + 16];
        #pragma unroll
        for (int n = 0; n < 2; ++n) {
            float bon = n ? bo1 : bo0;
            int cout = c0 + 16 * n;
            #pragma unroll
            for (int m = 0; m < 4; ++m) {
                int tok0 = 16 * m + 4 * g;
                int ph = tok0 >> 3, pw = tok0 & 7;
                f4 ov;
                #pragma unroll
                for (int i = 0; i < 4; ++i) {
                    float rv = bf2f((unsigned short)((resp[m][n][i >> 1] >> (16 * (i & 1))) & 0xFFFF));
                    ov[i] = oacc.a[m][n][i] + bon + rv;
                }
                *(f4*)(out + win_base + (long)cout * HWC + ph * Wd + pw) = ov;
            }
        }
    }
}

extern "C" void kernel_launch(void* const* d_in, const int* in_sizes, int n_in,
                              void* d_out, int out_size, void* d_ws, size_t ws_size,
                              hipStream_t stream) {
    (void)in_sizes; (void)n_in; (void)out_size; (void)ws_size;
    const float* y_lf = (const float*)d_in[0];
    const float* y_hf = (const float*)d_in[1];
    const float* g_lf = (const float*)d_in[2];
    const float* b_lf = (const float*)d_in[3];
    const float* g_hf = (const float*)d_in[4];
    const float* b_hf = (const float*)d_in[5];
    const float* Wq   = (const float*)d_in[6];
    const float* bq   = (const float*)d_in[7];
    const float* Wk   = (const float*)d_in[8];
    const float* bk   = (const float*)d_in[9];
    const float* Wv   = (const float*)d_in[10];
    const float* bv   = (const float*)d_in[11];
    const float* Wo   = (const float*)d_in[12];
    const float* bo   = (const float*)d_in[13];
    float* out = (float*)d_out;

    pcaf_precvt<<<dim3(1024), dim3(64), 0, stream>>>(
        Wq, bq, Wk, bk, Wv, Wo, g_lf, b_lf, g_hf, b_hf, d_ws);
    pcaf13_kernel<<<dim3(2048), dim3(1024), 0, stream>>>(
        y_lf, y_hf, bv, bo, d_ws, out);
}

// Round 14
// 418.508 us; speedup vs baseline: 1.3043x; 1.1753x over previous
//
#include <hip/hip_runtime.h>

typedef float  f4     __attribute__((ext_vector_type(4)));
typedef float  f32x4  __attribute__((ext_vector_type(4)));
typedef short  short8 __attribute__((ext_vector_type(8)));
typedef __bf16 bf16x8 __attribute__((ext_vector_type(8)));
typedef int    int4v  __attribute__((ext_vector_type(4)));
typedef unsigned short us4 __attribute__((ext_vector_type(4)));

__device__ __forceinline__ unsigned short f2bf(float f) {
    unsigned int u = __builtin_bit_cast(unsigned int, f);
    u += 0x7FFFu + ((u >> 16) & 1u);
    return (unsigned short)(u >> 16);
}
__device__ __forceinline__ float bf2f(unsigned short h) {
    unsigned int u = ((unsigned int)h) << 16;
    return __builtin_bit_cast(float, u);
}
__device__ __forceinline__ f32x4 mfma_bf16(short8 a, short8 b, f32x4 c) {
    return __builtin_amdgcn_mfma_f32_16x16x32_bf16(
        __builtin_bit_cast(bf16x8, a), __builtin_bit_cast(bf16x8, b), c, 0, 0, 0);
}
__device__ __forceinline__ int cvt_pk_bf16(float lo, float hi) {
    int d;
    asm("v_cvt_pk_bf16_f32 %0, %1, %2" : "=v"(d) : "v"(lo), "v"(hi));
    return d;
}
__device__ __forceinline__ int bperm(int addr, int src) {
    return __builtin_amdgcn_ds_bpermute(addr, src);
}

// ============================================================================
// Weight pre-conversion: fold LN gamma into Wq/Wk, cvt to bf16, store
// FRAGMENT-MAJOR: frag short-index = mat*65536 + ((ct*8 + k)*64 + lane)*8 + e
//   content[e] = W'[cout = ct*16 + (lane&15)][cin = k*32 + (lane>>4)*8 + e]
// ws: [0]Wq' [128K]Wk' [256K]Wv [384K]Wo
//     [512K] f32 consts: qc float2[256] {rsq,cbq} | kc float2[256] {rsk,cbk}
// ============================================================================
__global__ void pcaf_precvt(const float* __restrict__ Wq, const float* __restrict__ bq,
                            const float* __restrict__ Wk, const float* __restrict__ bk,
                            const float* __restrict__ Wv, const float* __restrict__ Wo,
                            const float* __restrict__ g_lf, const float* __restrict__ b_lf,
                            const float* __restrict__ g_hf, const float* __restrict__ b_hf,
                            void* __restrict__ ws) {
    const int mat  = blockIdx.x >> 8;      // 0=q 1=k 2=v 3=o
    const int row  = blockIdx.x & 255;     // cout
    const int lane = threadIdx.x;          // 0..63, 4 cin each
    const float* W = (mat == 0) ? Wq : (mat == 1) ? Wk : (mat == 2) ? Wv : Wo;
    f4 w = *(const f4*)(W + row * 256 + lane * 4);
    f4 wp = w;
    if (mat < 2) {
        const float* g = mat ? g_hf : g_lf;
        f4 gg = *(const f4*)(g + lane * 4);
        wp = w * gg;
    }
    us4 u;
    u[0] = f2bf(wp[0]); u[1] = f2bf(wp[1]); u[2] = f2bf(wp[2]); u[3] = f2bf(wp[3]);
    {
        const int ct   = row >> 4;
        const int l15r = row & 15;
        const int k_   = lane >> 3;          // cin block of 32
        const int g_   = (lane >> 1) & 3;    // 8-cin group
        const int e4   = (lane & 1) * 4;     // half of the 8-cin group
        unsigned short* dst = (unsigned short*)ws + mat * 65536 +
                              (((ct * 8 + k_) * 64) + g_ * 16 + l15r) * 8 + e4;
        *(us4*)dst = u;
    }
    if (mat < 2) {
        const float* b = mat ? b_hf : b_lf;
        f4 bb = *(const f4*)(b + lane * 4);
        float rsum = wp[0] + wp[1] + wp[2] + wp[3];
        float cb   = bb[0] * w[0] + bb[1] * w[1] + bb[2] * w[2] + bb[3] * w[3];
        #pragma unroll
        for (int d = 1; d < 64; d <<= 1) {
            rsum += __shfl_xor(rsum, d);
            cb   += __shfl_xor(cb, d);
        }
        if (lane == 0) {
            float* cons = (float*)((char*)ws + 524288);
            cons[mat * 512 + 2 * row]     = rsum;
            cons[mat * 512 + 2 * row + 1] = cb + (mat ? bk[row] : bq[row]);
        }
    }
}

// ============================================================================
// Main fused kernel: 512 threads (8 waves = 8 heads), ONE WINDOW per block,
// 256 VGPRs/wave (waves_per_eu 2,2). Fully-merged register flow:
// V,K,Q GEMMs (K/Q transposed + in-reg LN) + in-reg attention, 4 barriers.
// ============================================================================
constexpr int RS  = 528;         // bf16 tile row stride (16B aligned)
constexpr int HWC = 65536;       // H*W
constexpr int Wd  = 256;
constexpr int OA  = 0;           // lf raw (64 tok) -> O   (33792)
constexpr int OB  = 33792;       // hf raw (64 tok), stays raw (33792)
constexpr int OS  = 67584;       // LN stats: m_lf[64]|r_lf[64]|m_hf[64]|r_hf[64]

struct AccW { f32x4 a[4][2]; };  // rows = token tiles, cols = 2 cout tiles
struct AccT { f32x4 a[2][4]; };  // rows = 2 cout tiles, cols = 4 token tiles

__device__ __forceinline__ AccW gemmW(const char* base,
                                      const unsigned short* __restrict__ Wbw,
                                      int lane, int g, int l15) {
    AccW r;
    f32x4 z = {0.f, 0.f, 0.f, 0.f};
    #pragma unroll
    for (int m = 0; m < 4; ++m) { r.a[m][0] = z; r.a[m][1] = z; }
    #pragma unroll
    for (int half = 0; half < 2; ++half) {
        short8 w0[4], w1[4];
        #pragma unroll
        for (int k = 0; k < 4; ++k) {
            w0[k] = *(const short8*)(Wbw + (half * 4 + k) * 512 + lane * 8);
            w1[k] = *(const short8*)(Wbw + 4096 + (half * 4 + k) * 512 + lane * 8);
        }
        #pragma unroll
        for (int k = 0; k < 4; ++k) {
            #pragma unroll
            for (int m = 0; m < 4; ++m) {
                short8 am = *(const short8*)(base + (16 * m + l15) * RS +
                                             ((half * 4 + k) * 32 + g * 8) * 2);
                r.a[m][0] = mfma_bf16(am, w0[k], r.a[m][0]);
                r.a[m][1] = mfma_bf16(am, w1[k], r.a[m][1]);
            }
        }
    }
    return r;
}

// Transposed orientation: A = weight frags, B = token rows -> C[cout][token].
__device__ __forceinline__ AccT gemmWT(const char* base,
                                       const unsigned short* __restrict__ Wbw,
                                       int lane, int g, int l15) {
    AccT r;
    f32x4 z = {0.f, 0.f, 0.f, 0.f};
    #pragma unroll
    for (int n = 0; n < 4; ++n) { r.a[0][n] = z; r.a[1][n] = z; }
    #pragma unroll
    for (int half = 0; half < 2; ++half) {
        short8 w0[4], w1[4];
        #pragma unroll
        for (int k = 0; k < 4; ++k) {
            w0[k] = *(const short8*)(Wbw + (half * 4 + k) * 512 + lane * 8);
            w1[k] = *(const short8*)(Wbw + 4096 + (half * 4 + k) * 512 + lane * 8);
        }
        #pragma unroll
        for (int k = 0; k < 4; ++k) {
            #pragma unroll
            for (int n = 0; n < 4; ++n) {
                short8 tk = *(const short8*)(base + (16 * n + l15) * RS +
                                             ((half * 4 + k) * 32 + g * 8) * 2);
                r.a[0][n] = mfma_bf16(w0[k], tk, r.a[0][n]);
                r.a[1][n] = mfma_bf16(w1[k], tk, r.a[1][n]);
            }
        }
    }
    return r;
}

// C-layout -> A/B-frag repack (validated r12): two m-variants + ghi select.
__device__ __forceinline__ short8 repack4(const int* p0, const int* p1,
                                          int a0, int a1, bool ghi) {
    int4v t;
    #pragma unroll
    for (int j = 0; j < 4; ++j) {
        int ad = (j >> 1) ? a1 : a0;
        int v0 = bperm(ad, p0[j & 1]);
        int v1 = bperm(ad, p1[j & 1]);
        t[j] = ghi ? v1 : v0;
    }
    return __builtin_bit_cast(short8, t);
}

__global__ __attribute__((amdgpu_flat_work_group_size(512, 512), amdgpu_waves_per_eu(2, 2)))
void pcaf14_kernel(
    const float* __restrict__ y_lf, const float* __restrict__ y_hf,
    const float* __restrict__ bv, const float* __restrict__ bo,
    const void* __restrict__ ws, float* __restrict__ out)
{
    __shared__ __align__(16) char sm[68608];

    const unsigned short* wsq = (const unsigned short*)ws;
    const unsigned short* wsk = wsq + 65536;
    const unsigned short* wsv = wsq + 131072;
    const unsigned short* wso = wsq + 196608;
    const float* qc = (const float*)((const char*)ws + 524288);
    const float* kc = qc + 512;

    const int tid = threadIdx.x;
    const int bid = blockIdx.x;                      // 0..4095
    const int wi  = ((bid & 7) << 9) | (bid >> 3);   // XCD-contiguous chunks
    const int bb  = wi >> 10;                        // batch 0..3
    const int nh  = (wi >> 5) & 31;
    const int nw  = wi & 31;
    const long win_base = (long)bb * 256 * HWC + (long)(nh * 8) * Wd + nw * 8;

    const int wave = tid >> 6;        // 0..7 = head
    const int lane = tid & 63;
    const int g    = lane >> 4;
    const int l15  = lane & 15;
    const int c0   = 32 * wave + l15;

    // ---- P0: stage window as bf16; conflict-free LDS writes ----------------
    // thread = (tensor=tid>>8, channel-pair c2=(tid&255)>>1, pw-strip (tid&1)*4)
    {
        const int half = tid >> 8;           // 0: lf, 1: hf
        const int t8   = tid & 255;
        const int pw4  = (t8 & 1) * 4;
        const int c2   = t8 >> 1;            // 0..127
        const float* src = half ? y_hf : y_lf;
        const int dst  = half ? OB : OA;
        const float* gp = src + win_base + (long)(2 * c2) * HWC + pw4;
        #pragma unroll
        for (int hh = 0; hh < 2; ++hh) {
            f4 v0[4], v1[4];
            #pragma unroll
            for (int p = 0; p < 4; ++p) {
                int ph = hh * 4 + p;
                v0[p] = *(const f4*)(gp + ph * Wd);
                v1[p] = *(const f4*)(gp + ph * Wd + HWC);
            }
            #pragma unroll
            for (int p = 0; p < 4; ++p) {
                int ph = hh * 4 + p;
                int tok0 = ph * 8 + pw4;
                #pragma unroll
                for (int j = 0; j < 4; ++j) {
                    unsigned int pk = (unsigned int)f2bf(v0[p][j]) |
                                      ((unsigned int)f2bf(v1[p][j]) << 16);
                    *(unsigned int*)(sm + dst + (tok0 + j) * RS + c2 * 4) = pk;
                }
            }
        }
    }
    __syncthreads();   // BAR1

    // ---- P1: LN stats for 64 token-rows, both tensors ----------------------
    {
        const int t = tid >> 3, j = tid & 7;     // t: 0..63
        #pragma unroll
        for (int pass = 0; pass < 2; ++pass) {
            const int base = pass ? OB : OA;
            float sum = 0.f, ss = 0.f;
            #pragma unroll
            for (int r = 0; r < 4; ++r) {
                short8 raw = *(const short8*)(sm + base + t * RS + (j * 32 + r * 8) * 2);
                #pragma unroll
                for (int e = 0; e < 8; ++e) { float f = bf2f((unsigned short)raw[e]); sum += f; ss += f * f; }
            }
            sum += __shfl_xor(sum, 1); ss += __shfl_xor(ss, 1);
            sum += __shfl_xor(sum, 2); ss += __shfl_xor(ss, 2);
            sum += __shfl_xor(sum, 4); ss += __shfl_xor(ss, 4);
            float mean = sum * (1.f / 256.f);
            float rstd = rsqrtf(ss * (1.f / 256.f) - mean * mean + 1e-5f);
            if (j == 0) {
                float* S = (float*)(sm + OS);
                S[pass * 128 + t]      = mean;
                S[pass * 128 + 64 + t] = rstd;
            }
        }
    }
    __syncthreads();   // BAR2 (stats ready; tiles stable)

    const float* S = (const float*)(sm + OS);
    const int  a0  = ((2 * (g & 1)) * 16 + l15) * 4;
    const int  a1  = a0 + 64;
    const bool ghi = (g >> 1) & 1;
    f32x4 z = {0.f, 0.f, 0.f, 0.f};

    // ---- V GEMM (original orientation) -> vf frags in regs -----------------
    short8 vf[2][2];
    {
        AccW vacc = gemmW(sm + OB, wsv + wave * 8192, lane, g, l15);
        float bv0 = bv[c0], bv1 = bv[c0 + 16];
        int vp[4][2][2];
        #pragma unroll
        for (int m = 0; m < 4; ++m) {
            vp[m][0][0] = cvt_pk_bf16(vacc.a[m][0][0] + bv0, vacc.a[m][0][1] + bv0);
            vp[m][0][1] = cvt_pk_bf16(vacc.a[m][0][2] + bv0, vacc.a[m][0][3] + bv0);
            vp[m][1][0] = cvt_pk_bf16(vacc.a[m][1][0] + bv1, vacc.a[m][1][1] + bv1);
            vp[m][1][1] = cvt_pk_bf16(vacc.a[m][1][2] + bv1, vacc.a[m][1][3] + bv1);
        }
        #pragma unroll
        for (int kk = 0; kk < 2; ++kk)
            #pragma unroll
            for (int n2 = 0; n2 < 2; ++n2)
                vf[kk][n2] = repack4(vp[2 * kk][n2], vp[2 * kk + 1][n2], a0, a1, ghi);
    }

    // ---- K GEMM (transposed) -> in-reg LN -> kf frags ----------------------
    short8 kf[4];
    {
        AccT kacc = gemmWT(sm + OB, wsk + wave * 8192, lane, g, l15);
        float mh[4], rh[4];
        #pragma unroll
        for (int n = 0; n < 4; ++n) {
            mh[n] = S[128 + 16 * n + l15];
            rh[n] = S[192 + 16 * n + l15];
        }
        int kp[2][4][2];
        #pragma unroll
        for (int m = 0; m < 2; ++m) {
            int cb = 32 * wave + 16 * m + 4 * g;
            f4 c0v = *(const f4*)(kc + cb * 2);
            f4 c1v = *(const f4*)(kc + cb * 2 + 4);
            #pragma unroll
            for (int n = 0; n < 4; ++n) {
                float v0 = rh[n] * (kacc.a[m][n][0] - mh[n] * c0v[0]) + c0v[1];
                float v1 = rh[n] * (kacc.a[m][n][1] - mh[n] * c0v[2]) + c0v[3];
                float v2 = rh[n] * (kacc.a[m][n][2] - mh[n] * c1v[0]) + c1v[1];
                float v3 = rh[n] * (kacc.a[m][n][3] - mh[n] * c1v[2]) + c1v[3];
                kp[m][n][0] = cvt_pk_bf16(v0, v1);
                kp[m][n][1] = cvt_pk_bf16(v2, v3);
            }
        }
        #pragma unroll
        for (int x = 0; x < 4; ++x)
            kf[x] = repack4(kp[0][x], kp[1][x], a0, a1, ghi);
    }

    // ---- Q GEMM (transposed) -> in-reg LN+scale -> qf frags ----------------
    short8 qf[4];
    {
        AccT qacc = gemmWT(sm + OA, wsq + wave * 8192, lane, g, l15);
        const float SCALE = 0.17677669529663687f;   // 1/sqrt(32)
        float ml[4], rl[4];
        #pragma unroll
        for (int n = 0; n < 4; ++n) {
            ml[n] = S[16 * n + l15];
            rl[n] = S[64 + 16 * n + l15];
        }
        int qp[2][4][2];
        #pragma unroll
        for (int m = 0; m < 2; ++m) {
            int cb = 32 * wave + 16 * m + 4 * g;
            f4 c0v = *(const f4*)(qc + cb * 2);
            f4 c1v = *(const f4*)(qc + cb * 2 + 4);
            #pragma unroll
            for (int n = 0; n < 4; ++n) {
                float v0 = (rl[n] * (qacc.a[m][n][0] - ml[n] * c0v[0]) + c0v[1]) * SCALE;
                float v1 = (rl[n] * (qacc.a[m][n][1] - ml[n] * c0v[2]) + c0v[3]) * SCALE;
                float v2 = (rl[n] * (qacc.a[m][n][2] - ml[n] * c1v[0]) + c1v[1]) * SCALE;
                float v3 = (rl[n] * (qacc.a[m][n][3] - ml[n] * c1v[2]) + c1v[3]) * SCALE;
                qp[m][n][0] = cvt_pk_bf16(v0, v1);
                qp[m][n][1] = cvt_pk_bf16(v2, v3);
            }
        }
        #pragma unroll
        for (int x = 0; x < 4; ++x)
            qf[x] = repack4(qp[0][x], qp[1][x], a0, a1, ghi);
    }

    // ---- attention: fully in registers -------------------------------------
    f32x4 o[4][2];
    {
        #pragma unroll
        for (int c = 0; c < 4; ++c) { o[c][0] = z; o[c][1] = z; }

        #pragma unroll
        for (int c = 0; c < 4; ++c) {
            f32x4 stc[4];
            #pragma unroll
            for (int nk = 0; nk < 4; ++nk)
                stc[nk] = mfma_bf16(kf[nk], qf[c], z);

            float mx = stc[0][0];
            #pragma unroll
            for (int nk = 0; nk < 4; ++nk)
                #pragma unroll
                for (int i = 0; i < 4; ++i) mx = fmaxf(mx, stc[nk][i]);
            mx = fmaxf(mx, __shfl_xor(mx, 16));
            mx = fmaxf(mx, __shfl_xor(mx, 32));
            float sum = 0.f;
            #pragma unroll
            for (int nk = 0; nk < 4; ++nk)
                #pragma unroll
                for (int i = 0; i < 4; ++i) {
                    float e = __expf(stc[nk][i] - mx);
                    stc[nk][i] = e;
                    sum += e;
                }
            sum += __shfl_xor(sum, 16);
            sum += __shfl_xor(sum, 32);
            float is = 1.f / sum;

            int pq[4][2];
            #pragma unroll
            for (int nk = 0; nk < 4; ++nk) {
                pq[nk][0] = cvt_pk_bf16(stc[nk][0] * is, stc[nk][1] * is);
                pq[nk][1] = cvt_pk_bf16(stc[nk][2] * is, stc[nk][3] * is);
            }

            #pragma unroll
            for (int kk = 0; kk < 2; ++kk) {
                short8 pf = repack4(pq[2 * kk], pq[2 * kk + 1], a0, a1, ghi);
                o[c][0] = mfma_bf16(pf, vf[kk][0], o[c][0]);
                o[c][1] = mfma_bf16(pf, vf[kk][1], o[c][1]);
            }
        }
    }
    __syncthreads();   // BAR3 (all raw-A reads done block-wide)

    // ---- O -> A region (rows=tokens, cols=couts) ---------------------------
    #pragma unroll
    for (int c = 0; c < 4; ++c)
        #pragma unroll
        for (int i = 0; i < 4; ++i) {
            int t = 16 * c + 4 * g + i;
            *(unsigned short*)(sm + OA + t * RS + c0 * 2)        = f2bf(o[c][0][i]);
            *(unsigned short*)(sm + OA + t * RS + (c0 + 16) * 2) = f2bf(o[c][1][i]);
        }
    __syncthreads();   // BAR4

    // ---- P5: out-proj + bias + residual (from raw B), direct f4 stores -----
    {
        AccW oacc = gemmW(sm + OA, wso + wave * 8192, lane, g, l15);
        float bo0 = bo[c0], bo1 = bo[c0 + 16];
        #pragma unroll
        for (int n = 0; n < 2; ++n) {
            float bon = n ? bo1 : bo0;
            int cout = c0 + 16 * n;
            #pragma unroll
            for (int m = 0; m < 4; ++m) {
                int tok0 = 16 * m + 4 * g;
                int ph = tok0 >> 3, pw = tok0 & 7;
                f4 ov;
                #pragma unroll
                for (int i = 0; i < 4; ++i) {
                    float rv = bf2f(*(const unsigned short*)(
                        sm + OB + (tok0 + i) * RS + cout * 2));
                    ov[i] = oacc.a[m][n][i] + bon + rv;
                }
                *(f4*)(out + win_base + (long)cout * HWC + ph * Wd + pw) = ov;
            }
        }
    }
}

extern "C" void kernel_launch(void* const* d_in, const int* in_sizes, int n_in,
                              void* d_out, int out_size, void* d_ws, size_t ws_size,
                              hipStream_t stream) {
    (void)in_sizes; (void)n_in; (void)out_size; (void)ws_size;
    const float* y_lf = (const float*)d_in[0];
    const float* y_hf = (const float*)d_in[1];
    const float* g_lf = (const float*)d_in[2];
    const float* b_lf = (const float*)d_in[3];
    const float* g_hf = (const float*)d_in[4];
    const float* b_hf = (const float*)d_in[5];
    const float* Wq   = (const float*)d_in[6];
    const float* bq   = (const float*)d_in[7];
    const float* Wk   = (const float*)d_in[8];
    const float* bk   = (const float*)d_in[9];
    const float* Wv   = (const float*)d_in[10];
    const float* bv   = (const float*)d_in[11];
    const float* Wo   = (const float*)d_in[12];
    const float* bo   = (const float*)d_in[13];
    float* out = (float*)d_out;

    pcaf_precvt<<<dim3(1024), dim3(64), 0, stream>>>(
        Wq, bq, Wk, bk, Wv, Wo, g_lf, b_lf, g_hf, b_hf, d_ws);
    pcaf14_kernel<<<dim3(4096), dim3(512), 0, stream>>>(
        y_lf, y_hf, bv, bo, d_ws, out);
}